// Round 1
// 862.438 us; speedup vs baseline: 1.3088x; 1.3088x over previous
//
#include <hip/hip_runtime.h>
#include <hip/hip_bf16.h>
#include <stdint.h>

// Problem constants
#define DD   768
#define NS   23
#define NL   50
#define NB   4096

typedef float  floatx4 __attribute__((ext_vector_type(4)));
typedef __bf16 bf16x8  __attribute__((ext_vector_type(8)));

__device__ __forceinline__ unsigned short f2bf(float x) {
  unsigned int u = __float_as_uint(x);
  u += 0x7fffu + ((u >> 16) & 1u);          // RNE (inputs Gaussian, no NaN)
  return (unsigned short)(u >> 16);
}
__device__ __forceinline__ float bf2f(unsigned short v) {
  return __uint_as_float(((unsigned int)v) << 16);
}

// async 16B global->LDS (m97 pattern). LDS dest = wave-uniform base + lane*16.
__device__ __forceinline__ void gload_lds16(const void* g, void* s) {
  __builtin_amdgcn_global_load_lds((const __attribute__((address_space(1))) void*)g,
                                   (__attribute__((address_space(3))) void*)s, 16, 0, 0);
}

// ---------------- precompute kernels (tiny, once per call) ----------------
// q_miss[s,d] (bf16) = in_proj_w[d,:] . missing_table[s,:] + in_proj_b[d]; rows 23..31 zero
__global__ void k_qmiss(const float* __restrict__ ipw, const float* __restrict__ ipb,
                        const float* __restrict__ mt, unsigned short* __restrict__ qm) {
  int o = blockIdx.x * 256 + threadIdx.x;   // 32*768 = 96*256 exact
  int s = o / DD, d = o - s * DD;
  if (s < NS) {
    const float4* wr = (const float4*)(ipw + (size_t)d * DD);
    const float4* mr = (const float4*)(mt + (size_t)s * DD);
    float sum = ipb[d];
    for (int j = 0; j < DD / 4; ++j) {
      float4 a = wr[j], b = mr[j];
      sum += a.x * b.x + a.y * b.y + a.z * b.z + a.w * b.w;
    }
    qm[o] = f2bf(sum);
  } else {
    qm[o] = 0;
  }
}

// WT rows 0..767: predw^T, zero-padded to 64 cols
__global__ void k_pwT(const float* __restrict__ pw, float* __restrict__ WT) {
  int o = blockIdx.x * 256 + threadIdx.x;   // 768*64 = 192*256 exact
  int d = o >> 6, l = o & 63;
  WT[o] = (l < NL) ? pw[(size_t)l * DD + d] : 0.f;
}

// WT rows 768..1535: (pred_w @ out_proj_w)^T
__global__ void k_wopT(const float* __restrict__ pw, const float* __restrict__ opw,
                       float* __restrict__ WT) {
  int o = blockIdx.x * 256 + threadIdx.x;   // 50*768 = 150*256 exact
  int l = o / DD, d = o - l * DD;
  const float* pr = pw + (size_t)l * DD;
  float sum = 0.f;
  for (int j = 0; j < DD; ++j) sum += pr[j] * opw[(size_t)j * DD + d];
  WT[(size_t)(DD + d) * 64 + l] = sum;
}

// zero pad cols 50..63 of WT rows 768..1535
__global__ void k_wtz(float* __restrict__ WT) {
  int o = blockIdx.x * 256 + threadIdx.x;   // 768*14 = 10752 = 42*256 exact
  int d = o / 14, l = NL + (o - d * 14);
  WT[(size_t)(DD + d) * 64 + l] = 0.f;
}

// bop[l] = pred_w[l,:] . out_proj_b
__global__ void k_bop(const float* __restrict__ pw, const float* __restrict__ opb,
                      float* __restrict__ bop) {
  int l = threadIdx.x;
  if (l < NL) {
    const float* pr = pw + (size_t)l * DD;
    float sum = 0.f;
    for (int j = 0; j < DD; ++j) sum += pr[j] * opb[j];
    bop[l] = sum;
  }
}

// K/V weight rows fp32 -> bf16 (1536*768 elements, 294912 float4)
__global__ void cast_w(const float* __restrict__ src, unsigned short* __restrict__ dst) {
  int i = blockIdx.x * 256 + threadIdx.x;   // 1152 blocks exact
  float4 v = *(const float4*)(src + (size_t)i * 4);
  ushort4 u;
  u.x = f2bf(v.x); u.y = f2bf(v.y); u.z = f2bf(v.z); u.w = f2bf(v.w);
  *(ushort4*)(dst + (size_t)i * 4) = u;
}

// ---------------- compaction: count + exclusive scan ----------------
__global__ void count_k(const int* __restrict__ exist, int* __restrict__ cnt,
                        int b0, int bc) {
  int i = blockIdx.x * 256 + threadIdx.x;
  if (i < bc) {
    const int* e = exist + (size_t)(b0 + i) * NS;
    int c = 0;
#pragma unroll
    for (int s = 0; s < NS; ++s) c += e[s];
    cnt[i] = c;
  }
}

__global__ __launch_bounds__(1024) void scan_k(const int* __restrict__ cnt,
                                               int* __restrict__ offs,
                                               int* __restrict__ meta, int bc) {
  __shared__ int ps[1024];
  const int t = threadIdx.x;
  const int base = t * 4;
  int v0 = 0, v1 = 0, v2 = 0, v3 = 0, s = 0;
  if (base + 0 < bc) { v0 = s; s += cnt[base + 0]; }
  if (base + 1 < bc) { v1 = s; s += cnt[base + 1]; }
  if (base + 2 < bc) { v2 = s; s += cnt[base + 2]; }
  if (base + 3 < bc) { v3 = s; s += cnt[base + 3]; }
  ps[t] = s;
  __syncthreads();
  for (int off = 1; off < 1024; off <<= 1) {
    int x = (t >= off) ? ps[t - off] : 0;
    __syncthreads();
    ps[t] += x;
    __syncthreads();
  }
  const int excl = (t == 0) ? 0 : ps[t - 1];
  if (base + 0 < bc) offs[base + 0] = excl + v0;
  if (base + 1 < bc) offs[base + 1] = excl + v1;
  if (base + 2 < bc) offs[base + 2] = excl + v2;
  if (base + 3 < bc) offs[base + 3] = excl + v3;
  if (t == 1023) {
    int total = ps[1023];
    offs[bc] = total;
    meta[0] = (total + 127) >> 7;   // ntiles (128-row M tiles)
  }
}

// ---------------- cls cast (compacted: existing rows only) + masked row-sum ----
__global__ __launch_bounds__(192) void cast_cls(
    const float* __restrict__ cls, const int* __restrict__ exist,
    const float* __restrict__ mtab, unsigned short* __restrict__ Abf,
    float* __restrict__ sumex, const int* __restrict__ offs, int b0) {
  const int bl = blockIdx.x, b = b0 + bl, t = threadIdx.x;
  __shared__ int em[NS];
  if (t < NS) em[t] = exist[(size_t)b * NS + t];
  __syncthreads();
  int any = 0;
  for (int s = 0; s < NS; ++s) any |= em[s];
  const int d = t * 4;
  float4 sum = {0.f, 0.f, 0.f, 0.f};
  int row = offs[bl];
  for (int s = 0; s < NS; ++s) {
    if (em[s]) {
      float4 v = *(const float4*)(cls + ((size_t)b * NS + s) * DD + d);
      ushort4 u;
      u.x = f2bf(v.x); u.y = f2bf(v.y); u.z = f2bf(v.z); u.w = f2bf(v.w);
      *(ushort4*)(Abf + (size_t)row * DD + d) = u;
      sum.x += v.x; sum.y += v.y; sum.z += v.z; sum.w += v.w;
      ++row;
    }
  }
  if (!any) {
    for (int s = 0; s < NS; ++s) {
      float4 m = *(const float4*)(mtab + (size_t)s * DD + d);
      sum.x += m.x; sum.y += m.y; sum.z += m.z; sum.w += m.w;
    }
  }
  *(float4*)(sumex + (size_t)bl * DD + d) = sum;
}

// ---------------- K/V projection GEMM (m97 structure; compact rows + XCD swizzle) ----
__global__ __launch_bounds__(256, 2) void kv_gemm(
    const unsigned short* __restrict__ A, const unsigned short* __restrict__ W,
    const float* __restrict__ bias, unsigned short* __restrict__ C,
    const int* __restrict__ meta) {
  // active tiles are data-dependent (compact row count); grid is worst-case.
  const int ntiles = meta[0];
  const int na = ntiles * 12;
  const int lin = blockIdx.y * 12 + blockIdx.x;
  if (lin >= na) return;
  // bijective XCD-chunk swizzle over the ACTIVE tile range (m204 variant):
  // consecutive tile ids (sharing an A-tile, 12 per row-block) land on one XCD.
  const int xcd = lin & 7, idx = lin >> 3;
  const int q = na >> 3, r = na & 7;
  const int tl = (xcd < r ? xcd * (q + 1) : r * (q + 1) + (xcd - r) * q) + idx;
  const int ty = tl / 12, tx = tl - ty * 12;

  __shared__ __align__(16) unsigned short As[128 * 32];
  __shared__ __align__(16) unsigned short Bs[128 * 32];
  const int tid = threadIdx.x;
  const int wave = tid >> 6, lane = tid & 63;
  const int wm = wave >> 1, wn = wave & 1;
  const int lq = lane >> 4, lr = lane & 15;

  floatx4 acc[4][4];
#pragma unroll
  for (int a = 0; a < 4; ++a)
#pragma unroll
    for (int b = 0; b < 4; ++b) {
      acc[a][b][0] = 0.f; acc[a][b][1] = 0.f; acc[a][b][2] = 0.f; acc[a][b][3] = 0.f;
    }

  const unsigned short* ga[2]; const unsigned short* gb[2];
  unsigned short* sa[2]; unsigned short* sb[2];
#pragma unroll
  for (int j = 0; j < 2; ++j) {
    int c = (wave * 2 + j) * 64 + lane;
    int rr = c >> 2, kc = c & 3;
    ga[j] = A + ((size_t)ty * 128 + rr) * DD + kc * 8;
    gb[j] = W + ((size_t)tx * 128 + rr) * DD + kc * 8;
    sa[j] = &As[c * 8];
    sb[j] = &Bs[c * 8];
  }

  for (int k0 = 0; k0 < DD; k0 += 32) {
    gload_lds16(ga[0] + k0, sa[0]);
    gload_lds16(ga[1] + k0, sa[1]);
    gload_lds16(gb[0] + k0, sb[0]);
    gload_lds16(gb[1] + k0, sb[1]);
    __syncthreads();
    bf16x8 af[4], bq[4];
#pragma unroll
    for (int t = 0; t < 4; ++t) {
      af[t] = *(bf16x8*)&As[(wm * 64 + t * 16 + lr) * 32 + lq * 8];
      bq[t] = *(bf16x8*)&Bs[(wn * 64 + t * 16 + lr) * 32 + lq * 8];
    }
#pragma unroll
    for (int mt = 0; mt < 4; ++mt)
#pragma unroll
      for (int nt = 0; nt < 4; ++nt)
        acc[mt][nt] = __builtin_amdgcn_mfma_f32_16x16x32_bf16(af[mt], bq[nt], acc[mt][nt], 0, 0, 0);
    __syncthreads();
  }

  const int bm = ty * 128 + wm * 64;
  const int bn = tx * 128 + wn * 64;
#pragma unroll
  for (int nt = 0; nt < 4; ++nt) {
    int col = bn + nt * 16 + lr;
    float bb = bias[col];
#pragma unroll
    for (int mt = 0; mt < 4; ++mt) {
#pragma unroll
      for (int i = 0; i < 4; ++i) {
        int row = bm + mt * 16 + lq * 4 + i;
        C[(size_t)row * 1536 + col] = f2bf(acc[mt][nt][i] + bb);
      }
    }
  }
}

// ---------------- attention: one wave per (sample, head); compact K/V ----------
__global__ __launch_bounds__(256) void attn_ctx(
    const unsigned short* __restrict__ KV, const unsigned short* __restrict__ qmb,
    const int* __restrict__ exist, const int* __restrict__ offs,
    float* __restrict__ cvec, float* __restrict__ nuarr, int b0) {
  const int lane = threadIdx.x & 63;
  const int wgid = (blockIdx.x << 2) | (threadIdx.x >> 6);
  const int bl = wgid >> 3, h = wgid & 7;
  const int b = b0 + bl;
  const int lr = lane & 15, lq = lane >> 4;

  const int base = offs[bl];
  const int cnt = offs[bl + 1] - base;   // # existing sections = # compact K/V rows

  int ev = 0;
  if (lane < NS) ev = exist[(size_t)b * NS + lane];
  const unsigned long long emask = __ballot(lane < NS && ev != 0);
  const bool hasany = (emask != 0ull);
  if (h == 0 && lane == 0)
    nuarr[bl] = hasany ? (float)(NS - __popcll(emask)) : 0.f;

  // scores C[q][key]: 2x2 tiles of mfma 16x16x32 over the 96 head dims.
  // keys are the COMPACT rows [0,cnt); rows >= cnt read garbage, masked below.
  floatx4 acc[2][2];
#pragma unroll
  for (int mt = 0; mt < 2; ++mt)
#pragma unroll
    for (int nt = 0; nt < 2; ++nt) {
      acc[mt][nt][0] = 0.f; acc[mt][nt][1] = 0.f; acc[mt][nt][2] = 0.f; acc[mt][nt][3] = 0.f;
    }
  const unsigned short* qbase = qmb + h * 96;
  const unsigned short* kbase = KV + (size_t)base * 1536 + h * 96;
#pragma unroll
  for (int ks = 0; ks < 3; ++ks) {
    const int ko = ks * 32 + lq * 8;
    bf16x8 a0 = *(const bf16x8*)(qbase + (size_t)lr * DD + ko);
    bf16x8 a1 = *(const bf16x8*)(qbase + (size_t)(16 + lr) * DD + ko);
    bf16x8 b0 = *(const bf16x8*)(kbase + (size_t)lr * 1536 + ko);
    bf16x8 b1 = *(const bf16x8*)(kbase + (size_t)(16 + lr) * 1536 + ko);
    acc[0][0] = __builtin_amdgcn_mfma_f32_16x16x32_bf16(a0, b0, acc[0][0], 0, 0, 0);
    acc[0][1] = __builtin_amdgcn_mfma_f32_16x16x32_bf16(a0, b1, acc[0][1], 0, 0, 0);
    acc[1][0] = __builtin_amdgcn_mfma_f32_16x16x32_bf16(a1, b0, acc[1][0], 0, 0, 0);
    acc[1][1] = __builtin_amdgcn_mfma_f32_16x16x32_bf16(a1, b1, acc[1][1], 0, 0, 0);
  }

  // mask + per-row softmax (rows span the 16 lanes of a quad-group) + fold.
  // compact keys: key j valid iff j < cnt (all compact rows are existing sections).
  const float scale = 0.10206207261596575f;  // 96^-0.5
  const bool v0 = lr < cnt;
  const bool v1 = (16 + lr) < cnt;
  float wk0 = 0.f, wk1 = 0.f;
#pragma unroll
  for (int mt = 0; mt < 2; ++mt) {
#pragma unroll
    for (int i = 0; i < 4; ++i) {
      const int r = mt * 16 + lq * 4 + i;
      float s0 = v0 ? acc[mt][0][i] * scale : -1e30f;
      float s1 = v1 ? acc[mt][1][i] * scale : -1e30f;
      float mx = fmaxf(s0, s1);
      mx = fmaxf(mx, __shfl_xor(mx, 1));
      mx = fmaxf(mx, __shfl_xor(mx, 2));
      mx = fmaxf(mx, __shfl_xor(mx, 4));
      mx = fmaxf(mx, __shfl_xor(mx, 8));
      float e0 = __expf(s0 - mx), e1 = __expf(s1 - mx);
      float sm = e0 + e1;
      sm += __shfl_xor(sm, 1);
      sm += __shfl_xor(sm, 2);
      sm += __shfl_xor(sm, 4);
      sm += __shfl_xor(sm, 8);
      const bool rmiss = hasany && (r < NS) && !((emask >> r) & 1ull);
      float w = rmiss ? (1.f / sm) : 0.f;
      wk0 += e0 * w;
      wk1 += e1 * w;
    }
  }
  wk0 += __shfl_xor(wk0, 16); wk0 += __shfl_xor(wk0, 32);
  wk1 += __shfl_xor(wk1, 16); wk1 += __shfl_xor(wk1, 32);

  // ctx[d] = sum over compact keys k < cnt of Wk[k] * V[k][d]
  const unsigned short* vbase = KV + (size_t)base * 1536 + 768 + h * 96;
  float ca = 0.f, cb = 0.f;
#pragma unroll 1
  for (int k = 0; k < cnt; ++k) {
    float wkk = (k < 16) ? __shfl(wk0, k) : __shfl(wk1, k - 16);
    const unsigned short* vr = vbase + (size_t)k * 1536;
    ca += wkk * bf2f(vr[lane]);
    cb += wkk * bf2f(vr[64 + lane]);   // lanes>=32 overread into padded rows; discarded
  }
  float* co = cvec + (size_t)bl * DD + h * 96;
  co[lane] = ca;
  if (lane < 32) co[64 + lane] = cb;
}

// ---------------- logits: wave = 4 samples, lane = label ----------------
__global__ __launch_bounds__(256) void logits_k(
    const float* __restrict__ sumex, const float* __restrict__ cvec,
    const float* __restrict__ WT, const float* __restrict__ bop,
    const float* __restrict__ predb, const float* __restrict__ nuarr,
    float* __restrict__ out, int b0) {
  const int lane = threadIdx.x & 63;
  const int wv = (blockIdx.x << 2) | (threadIdx.x >> 6);
  const int s0 = wv * 4;
  float acc[4] = {0.f, 0.f, 0.f, 0.f};
  const float* xs[4]; const float* xc[4];
#pragma unroll
  for (int u = 0; u < 4; ++u) {
    xs[u] = sumex + (size_t)(s0 + u) * DD;
    xc[u] = cvec + (size_t)(s0 + u) * DD;
  }
  for (int d = 0; d < DD; d += 4) {
    float w0 = WT[(size_t)(d + 0) * 64 + lane];
    float w1 = WT[(size_t)(d + 1) * 64 + lane];
    float w2 = WT[(size_t)(d + 2) * 64 + lane];
    float w3 = WT[(size_t)(d + 3) * 64 + lane];
#pragma unroll
    for (int u = 0; u < 4; ++u) {
      float4 x = *(const float4*)(xs[u] + d);
      acc[u] += x.x * w0 + x.y * w1 + x.z * w2 + x.w * w3;
    }
  }
  for (int d = 0; d < DD; d += 4) {
    float w0 = WT[(size_t)(DD + d + 0) * 64 + lane];
    float w1 = WT[(size_t)(DD + d + 1) * 64 + lane];
    float w2 = WT[(size_t)(DD + d + 2) * 64 + lane];
    float w3 = WT[(size_t)(DD + d + 3) * 64 + lane];
#pragma unroll
    for (int u = 0; u < 4; ++u) {
      float4 x = *(const float4*)(xc[u] + d);
      acc[u] += x.x * w0 + x.y * w1 + x.z * w2 + x.w * w3;
    }
  }
  if (lane < NL) {
    float bo = bop[lane], pb = predb[lane];
#pragma unroll
    for (int u = 0; u < 4; ++u)
      out[(size_t)(b0 + s0 + u) * NL + lane] = pb + (acc[u] + nuarr[s0 + u] * bo) * (1.0f / 23.0f);
  }
}

// ---------------- host ----------------
extern "C" void kernel_launch(void* const* d_in, const int* in_sizes, int n_in,
                              void* d_out, int out_size, void* d_ws, size_t ws_size,
                              hipStream_t stream) {
  const float* cls  = (const float*)d_in[0];
  const float* mtab = (const float*)d_in[1];
  const float* ipw  = (const float*)d_in[2];
  const float* ipb  = (const float*)d_in[3];
  const float* opw  = (const float*)d_in[4];
  const float* opb  = (const float*)d_in[5];
  const float* pw   = (const float*)d_in[6];
  const float* pb   = (const float*)d_in[7];
  const int*   em   = (const int*)d_in[8];
  float* outp = (float*)d_out;
  (void)in_sizes; (void)n_in; (void)out_size;

  // fixed ws: qmb 32x768 bf16 (49152) | WT 1536x64 f32 (393216) | bop (256) | meta (64)
  //           | Wbf 1536x768 bf16 (2359296)
  char* ws = (char*)d_ws;
  unsigned short* qmb  = (unsigned short*)ws;
  float*          WT   = (float*)(ws + 49152);
  float*          bopb = (float*)(ws + 49152 + 393216);
  int*            meta = (int*)(ws + 49152 + 393216 + 256);
  unsigned short* Wbf  = (unsigned short*)(ws + 49152 + 393216 + 256 + 64);
  const size_t fixed = 49152 + 393216 + 256 + 64 + 2359296;   // 2801984
  char* cb = ws + fixed;
  const size_t kvpad = 32 * 1536 * 2;                         // attn score-tile overread pad
  const size_t per   = 3072 + 35328 + 70656 + 3072 + 4 + 8;   // sumex+Abf+KV+cvec+nuarr+cnt+offs

  int Bc = 128;
  if (ws_size > fixed + kvpad + 256) {
    size_t n = (ws_size - fixed - kvpad - 256) / per;
    if (n > (size_t)NB) n = NB;
    int nn = (int)((n / 128) * 128);
    if (nn > Bc) Bc = nn;
  }

  k_qmiss<<<dim3(96),   dim3(256), 0, stream>>>(ipw, ipb, mtab, qmb);
  k_pwT  <<<dim3(192),  dim3(256), 0, stream>>>(pw, WT);
  k_wopT <<<dim3(150),  dim3(256), 0, stream>>>(pw, opw, WT);
  k_wtz  <<<dim3(42),   dim3(256), 0, stream>>>(WT);
  k_bop  <<<dim3(1),    dim3(64),  0, stream>>>(pw, opb, bopb);
  cast_w <<<dim3(1152), dim3(256), 0, stream>>>(ipw + (size_t)DD * DD, Wbf);

  for (int b0 = 0; b0 < NB; b0 += Bc) {
    int bc = NB - b0; if (bc > Bc) bc = Bc;
    size_t o = 0;
    float*          sumex = (float*)(cb + o);          o += (size_t)bc * 3072;
    unsigned short* Abf   = (unsigned short*)(cb + o); o += (size_t)bc * 35328;
    unsigned short* KVp   = (unsigned short*)(cb + o); o += (size_t)bc * 70656 + kvpad;
    float*          cvec  = (float*)(cb + o);          o += (size_t)bc * 3072;
    float*          nuarr = (float*)(cb + o);          o += (size_t)bc * 4;
    int*            cnt   = (int*)(cb + o);            o += (size_t)bc * 4;
    int*            offs  = (int*)(cb + o);

    count_k <<<dim3((bc + 255) / 256), dim3(256),  0, stream>>>(em, cnt, b0, bc);
    scan_k  <<<dim3(1),                dim3(1024), 0, stream>>>(cnt, offs, meta, bc);
    cast_cls<<<dim3(bc),               dim3(192),  0, stream>>>(cls, em, mtab, Abf, sumex, offs, b0);
    dim3 g(12, bc * NS / 128);
    kv_gemm <<<g,                      dim3(256),  0, stream>>>(Abf, Wbf, ipb + DD, KVp, meta);
    attn_ctx<<<dim3(bc * 2),           dim3(256),  0, stream>>>(KVp, qmb, em, offs, cvec, nuarr, b0);
    logits_k<<<dim3(bc / 16),          dim3(256),  0, stream>>>(sumex, cvec, WT, bopb, pb, nuarr, outp, b0);
  }
}